// Round 1
// baseline (162.858 us; speedup 1.0000x reference)
//
#include <hip/hip_runtime.h>
#include <math.h>

#define N_S 32
#define C_DIM 3
#define F_DIM 3277
#define T_DIM 256
#define FT (F_DIM * T_DIM)        /* 838912  */
#define CFT (C_DIM * FT)          /* 2516736 */
#define FC_IDX 1084
#define NOISE_LO_END 1638         /* noise rows: [0,1638) and [1966,3277) */
#define SKIP 328
#define N_NOISE 2949
#define RPC 12                    /* noise rows per chunk (3 per wave) */
#define NCHUNK ((N_NOISE + RPC - 1) / RPC)  /* 246 */

struct WS {
  float              noise_partial[N_S][256];
  int                mid[N_S];
  int                hb[N_S];
  unsigned long long tbits[N_S][4];
  unsigned long long mask[F_DIM][4];
};

// ---------------- kernel 1: noise partial sums (the big read) ----------------
__global__ __launch_bounds__(256) void k_noise(const float* __restrict__ x, WS* __restrict__ ws) {
  int blk   = blockIdx.x;
  int n     = blk / NCHUNK;
  int chunk = blk - n * NCHUNK;
  int w     = threadIdx.x >> 6;   // wave id 0..3
  int lane  = threadIdx.x & 63;
  float s = 0.f;
  const float* base_n = x + (size_t)n * CFT + lane * 4;
  #pragma unroll
  for (int i = 0; i < RPC / 4; ++i) {
    int j = chunk * RPC + w + i * 4;          // noise-row index
    if (j < N_NOISE) {
      int k = (j < NOISE_LO_END) ? j : j + SKIP;  // actual freq row
      const float* p = base_n + (size_t)k * T_DIM;
      #pragma unroll
      for (int c = 0; c < C_DIM; ++c) {
        float4 v = *reinterpret_cast<const float4*>(p + (size_t)c * FT);
        s += fabsf(v.x) + fabsf(v.y) + fabsf(v.z) + fabsf(v.w);
      }
    }
  }
  // wave64 reduce
  for (int off = 32; off; off >>= 1) s += __shfl_down(s, off);
  __shared__ double wsum[4];
  if (lane == 0) wsum[w] = (double)s;
  __syncthreads();
  if (threadIdx.x == 0) {
    ws->noise_partial[n][chunk] = (float)(wsum[0] + wsum[1] + wsum[2] + wsum[3]);
  }
}

// ------------- kernel 2: per-sample stats (argmax, sig, snr, hb) -------------
__global__ __launch_bounds__(256) void k_stats(const float* __restrict__ x, WS* __restrict__ ws) {
  int n = blockIdx.x;
  int t = threadIdx.x;
  const float* p = x + (size_t)n * CFT + (size_t)FC_IDX * T_DIM + t;
  float m = fabsf(p[0]) + fabsf(p[FT]) + fabsf(p[2 * FT]);

  __shared__ float  smag[256];
  __shared__ float  sv[256];
  __shared__ int    si[256];
  __shared__ double sd[256];
  smag[t] = m; sv[t] = m; si[t] = t;
  sd[t] = (t < NCHUNK) ? (double)ws->noise_partial[n][t] : 0.0;
  __syncthreads();
  for (int s = 128; s > 0; s >>= 1) {
    if (t < s) {
      // argmax with first-occurrence tie-break (matches jnp.argmax)
      if (sv[t + s] > sv[t] || (sv[t + s] == sv[t] && si[t + s] < si[t])) {
        sv[t] = sv[t + s]; si[t] = si[t + s];
      }
      sd[t] += sd[t + s];
    }
    __syncthreads();
  }
  if (t == 0) {
    int mid = si[0];
    double noise_d = sd[0] / ((double)N_NOISE * (double)T_DIM);
    int lo = mid - 8; if (lo < 0) lo = 0;
    int hi = mid + 8; if (hi > T_DIM) hi = T_DIM;
    double sig_d = 0.0;
    for (int tt = lo; tt < hi; ++tt) sig_d += (double)smag[tt];
    float sig = (float)sig_d, noise = (float)noise_d;
    float d   = sig - noise;
    float snr = 10.0f * log10f((d * d) / (noise * noise));
    float hbf = 12.5f * (snr - 20.0f) + 27.0f;
    int hb = (int)truncf(hbf);
    if (hb < 8) hb = 8;
    ws->mid[n] = mid;
    ws->hb[n]  = hb;
    int wlo = mid - 8, whi = mid + 8;
    #pragma unroll
    for (int wd = 0; wd < 4; ++wd) {
      int base = wd * 64;
      int a = wlo - base; if (a < 0) a = 0;
      int b = whi - base; if (b > 64) b = 64;
      unsigned long long msk = 0ULL;
      if (b > a) {
        unsigned long long hiM = (b >= 64) ? ~0ULL : ((1ULL << b) - 1ULL);
        unsigned long long loM = (1ULL << a) - 1ULL;   // a < 64 guaranteed here
        msk = hiM & ~loM;
      }
      ws->tbits[n][wd] = msk;
    }
  }
}

// --------------- kernel 3: union mask over samples, per freq row -------------
__global__ __launch_bounds__(256) void k_mask(WS* __restrict__ ws) {
  int f = blockIdx.x * blockDim.x + threadIdx.x;
  if (f >= F_DIM) return;
  unsigned long long m0 = 0, m1 = 0, m2 = 0, m3 = 0;
  #pragma unroll 4
  for (int n = 0; n < N_S; ++n) {
    int hb = ws->hb[n];
    if (f >= FC_IDX - hb && f < FC_IDX + hb) {
      m0 |= ws->tbits[n][0]; m1 |= ws->tbits[n][1];
      m2 |= ws->tbits[n][2]; m3 |= ws->tbits[n][3];
    }
  }
  ws->mask[f][0] = m0; ws->mask[f][1] = m1;
  ws->mask[f][2] = m2; ws->mask[f][3] = m3;
}

// ------------------- kernel 4: masked copy (the big write) -------------------
__global__ __launch_bounds__(256) void k_out(const float4* __restrict__ xv,
                                             float4* __restrict__ ov,
                                             const WS* __restrict__ ws) {
  const int total4 = (N_S * CFT) / 4;   // 20,133,888
  for (int idx = blockIdx.x * blockDim.x + threadIdx.x; idx < total4;
       idx += gridDim.x * blockDim.x) {
    int t4   = idx & 63;                // float4 index within the T row
    int rest = idx >> 6;
    int f    = rest % F_DIM;
    unsigned long long word = ws->mask[f][t4 >> 4];
    int bits = (int)(word >> ((t4 & 15) * 4)) & 0xF;
    float4 r = {0.f, 0.f, 0.f, 0.f};
    if (bits) {
      float4 v = xv[idx];
      if (bits & 1) r.x = v.x;
      if (bits & 2) r.y = v.y;
      if (bits & 4) r.z = v.z;
      if (bits & 8) r.w = v.w;
    }
    ov[idx] = r;
  }
}

extern "C" void kernel_launch(void* const* d_in, const int* in_sizes, int n_in,
                              void* d_out, int out_size, void* d_ws, size_t ws_size,
                              hipStream_t stream) {
  const float* x   = (const float*)d_in[0];
  float*       out = (float*)d_out;
  WS*          ws  = (WS*)d_ws;

  k_noise<<<N_S * NCHUNK, 256, 0, stream>>>(x, ws);
  k_stats<<<N_S, 256, 0, stream>>>(x, ws);
  k_mask<<<(F_DIM + 255) / 256, 256, 0, stream>>>(ws);
  k_out<<<8192, 256, 0, stream>>>((const float4*)x, (float4*)out, ws);
}